// Round 5
// baseline (407.097 us; speedup 1.0000x reference)
//
#include <hip/hip_runtime.h>

typedef float f32x4 __attribute__((ext_vector_type(4)));
typedef __bf16 bf16x8 __attribute__((ext_vector_type(8)));

#define WTHR 0.001f

// ---------------- ws layout (bytes) ----------------
static constexpr size_t WS_A1   = 0;                       // ushort[8388608] bf16 bits, NHWC
static constexpr size_t WS_A2   = 16777216;                // ushort[8388608] NHWC
static constexpr size_t WS_OUT1 = 33554432;                // float[8388608], NCHW (numpy memory order!)
static constexpr size_t WS_TW1  = 67108864;                // ushort[9*256*256]
static constexpr size_t WS_TW2  = 68288512;                // ushort[9*256*256]
static constexpr size_t WS_TB   = 69468160;                // float[8*256]
static constexpr size_t WS_GN1  = 69476352;                // float[512]: mean[256], rstd[256]
static constexpr size_t WS_GN2  = 69478400;                // float[512]: mean[256], rstd[256]

// ---------------- GN stats: EXACT numpy-fp32 pairwise replication ----------------
// One block per (b,g). Slab = 32768 contiguous floats (NCHW). numpy pairwise_sum:
// 128-elem base case (8 accumulators stride 8, combine ((r0+r1)+(r2+r3))+((r4+r5)+(r6+r7))),
// balanced binary tree above. rstd = 1.0/sqrt(var+eps), both correctly rounded fp32.
__global__ __launch_bounds__(256)
void k_gn_stats(const float* __restrict__ x, float* __restrict__ mean, float* __restrict__ rstd)
{
    int bg = blockIdx.x;                     // b*32+g
    int t = threadIdx.x;
    const float4* A = reinterpret_cast<const float4*>(x + (size_t)bg * 32768 + (size_t)t * 128);
    __shared__ float P[256];

    // ---- pass 1: mean (numpy order) ----
    float r0, r1, r2, r3, r4, r5, r6, r7;
    {
        float4 v0 = A[0], v1 = A[1];
        r0 = v0.x; r1 = v0.y; r2 = v0.z; r3 = v0.w;
        r4 = v1.x; r5 = v1.y; r6 = v1.z; r7 = v1.w;
        for (int i = 2; i < 32; i += 2) {
            float4 u0 = A[i], u1 = A[i + 1];
            r0 += u0.x; r1 += u0.y; r2 += u0.z; r3 += u0.w;
            r4 += u1.x; r5 += u1.y; r6 += u1.z; r7 += u1.w;
        }
    }
    P[t] = ((r0 + r1) + (r2 + r3)) + ((r4 + r5) + (r6 + r7));
    __syncthreads();
    #pragma unroll
    for (int st = 1; st < 256; st <<= 1) {
        if ((t & (2 * st - 1)) == 0) P[t] = P[t] + P[t + st];
        __syncthreads();
    }
    float mn = P[0] / 32768.0f;              // /2^15 exact
    __syncthreads();

    // ---- pass 2: var = mean((x-mn)^2), numpy order, no FMA contraction ----
    {
        float4 v0 = A[0], v1 = A[1];
        float d;
        d = v0.x - mn; r0 = __fmul_rn(d, d);
        d = v0.y - mn; r1 = __fmul_rn(d, d);
        d = v0.z - mn; r2 = __fmul_rn(d, d);
        d = v0.w - mn; r3 = __fmul_rn(d, d);
        d = v1.x - mn; r4 = __fmul_rn(d, d);
        d = v1.y - mn; r5 = __fmul_rn(d, d);
        d = v1.z - mn; r6 = __fmul_rn(d, d);
        d = v1.w - mn; r7 = __fmul_rn(d, d);
        for (int i = 2; i < 32; i += 2) {
            float4 u0 = A[i], u1 = A[i + 1];
            d = u0.x - mn; r0 = r0 + __fmul_rn(d, d);
            d = u0.y - mn; r1 = r1 + __fmul_rn(d, d);
            d = u0.z - mn; r2 = r2 + __fmul_rn(d, d);
            d = u0.w - mn; r3 = r3 + __fmul_rn(d, d);
            d = u1.x - mn; r4 = r4 + __fmul_rn(d, d);
            d = u1.y - mn; r5 = r5 + __fmul_rn(d, d);
            d = u1.z - mn; r6 = r6 + __fmul_rn(d, d);
            d = u1.w - mn; r7 = r7 + __fmul_rn(d, d);
        }
    }
    P[t] = ((r0 + r1) + (r2 + r3)) + ((r4 + r5) + (r6 + r7));
    __syncthreads();
    #pragma unroll
    for (int st = 1; st < 256; st <<= 1) {
        if ((t & (2 * st - 1)) == 0) P[t] = P[t] + P[t + st];
        __syncthreads();
    }
    if (t == 0) {
        float var = P[0] / 32768.0f;
        mean[bg] = mn;
        // correctly-rounded fp32: 1.0/sqrt(var+eps)  (NOT v_rsq approx!)
        rstd[bg] = __fdiv_rn(1.0f, __fsqrt_rn(var + 1e-5f));
    }
}

// ---------------- ternarize + transpose weights: W[co][ci][kh][kw] -> twT[off][co][ci] ----------------
__global__ __launch_bounds__(256)
void k_tern(const float* __restrict__ W, unsigned short* __restrict__ twT)
{
    int idx = blockIdx.x * 256 + threadIdx.x;        // 589824 = 2304*256 exact
    int off = idx >> 16;
    int rem = idx & 65535;
    int co = rem >> 8, ci = rem & 255;
    float w = W[(size_t)((co << 8) | ci) * 9 + off];
    unsigned short t = (w > WTHR) ? (unsigned short)0x3F80u
                     : ((w < -WTHR) ? (unsigned short)0xBF80u : (unsigned short)0u);
    twT[idx] = t;
}

// ---------------- time bias: fp32 sequential FMA over ascending k (BLAS microkernel order) ----------------
__global__ __launch_bounds__(256)
void k_tb(const float* __restrict__ te, const float* __restrict__ Wt, const float* __restrict__ bt,
          float* __restrict__ tb)
{
    int b = blockIdx.x, co = threadIdx.x;
    const float* wrow = Wt + (size_t)co * 512;
    const float* trow = te + (size_t)b * 512;
    float acc = 0.f;
    for (int t = 0; t < 512; ++t) {
        float w = wrow[t];
        float tw = (w > WTHR) ? 1.f : ((w < -WTHR) ? -1.f : 0.f);
        acc = __fmaf_rn(fmaxf(trow[t], 0.f), tw, acc);   // exact ±add; sequential rounding
    }
    tb[(b << 8) + co] = acc + bt[co];
}

// ---------------- norm + relu + quant: src NCHW f32 -> dst NHWC bf16 bits {0,1} ----------------
__global__ __launch_bounds__(256)
void k_norm_quant(const float* __restrict__ x, const float* __restrict__ gamma, const float* __restrict__ beta,
                  const float* __restrict__ mean, const float* __restrict__ rstd,
                  const float* __restrict__ scale, unsigned short* __restrict__ a)
{
    int blk = blockIdx.x;            // 512 = b*64+h
    int b = blk >> 6, h = blk & 63;
    int tid = threadIdx.x;
    __shared__ unsigned short T[64 * 264];     // [w][c], pitch 264
    float s = fabsf(*scale);
    int w = tid & 63;
    int c0 = tid >> 6;              // 0..3
    for (int i = 0; i < 64; ++i) {
        int c = (c0 << 6) + i;
        float xv = x[((size_t)((b << 8) + c) << 12) + (h << 6) + w];
        int bg = (b << 5) + (c >> 3);
        float y = __fmul_rn(xv - mean[bg], rstd[bg]);   // sub, then mul by recip (np order)
        y = y * gamma[c] + beta[c];                     // gamma=1,beta=0: exact
        y = fmaxf(y, 0.f);
        T[w * 264 + c] = (rintf(__fdiv_rn(y, s)) >= 1.0f) ? (unsigned short)0x3F80u : (unsigned short)0u;
    }
    __syncthreads();
    unsigned short* dst = a + ((size_t)blk << 14);
    #pragma unroll
    for (int j = 0; j < 8; ++j) {
        int e = (j << 11) + (tid << 3);          // element = w*256 + c
        int ww = e >> 8, c = e & 255;
        *reinterpret_cast<uint4*>(dst + e) = *reinterpret_cast<const uint4*>(&T[ww * 264 + c]);
    }
}

// ---------------- conv 3x3, implicit GEMM, bf16 MFMA ----------------
// O==0 (conv1): D[m=w][n=co] = acts * W ; out NCHW f32, v = (I + b1) + tb  (np ufunc order)
// O==1 (conv2): D[m=co][n=w] = W * acts ; out NCHW f32, v = (I + b2) + x
template<int O>
__global__ __launch_bounds__(256)
void k_conv(const unsigned short* __restrict__ acts,   // NHWC bf16 bits [8][64][64][256]
            const unsigned short* __restrict__ twT,    // [9][256][256] bf16 bits
            const float* __restrict__ bias,            // [256]
            const float* __restrict__ tb,              // [8][256] (O==0)
            const float* __restrict__ scale,
            const float* __restrict__ resid,           // x NCHW (O==1)
            float* __restrict__ out)                   // NCHW f32
{
    int blk = blockIdx.x;               // 512 = b*64+h
    int b = blk >> 6, h = blk & 63;
    int tid = threadIdx.x;
    int lane = tid & 63, wv = tid >> 6;
    int l15 = lane & 15, l4 = lane >> 4;

    __shared__ union ShMem {
        unsigned short stage[3 * 66 * 64];   // 25344 B: staged input rows, XOR-swizzled
        float outbuf[128 * 66];              // 33792 B: epilogue transpose buffer
    } sh;

    f32x4 acc[4][4];
    #pragma unroll
    for (int i = 0; i < 4; ++i)
        #pragma unroll
        for (int j = 0; j < 4; ++j)
            acc[i][j] = (f32x4){0.f, 0.f, 0.f, 0.f};

    for (int cc = 0; cc < 4; ++cc) {             // ci chunks of 64
        __syncthreads();
        // stage acts chunk: rows h-1..h+1, w' = w+1 in [0,66), zero halo
        for (int idx = tid; idx < 3 * 66 * 8; idx += 256) {
            int dh  = idx / 528;
            int rem = idx - dh * 528;
            int wp  = rem >> 3;
            int c16 = rem & 7;
            int hh = h + dh - 1;
            int w  = wp - 1;
            uint4 v = {0u, 0u, 0u, 0u};
            if ((unsigned)hh < 64u && (unsigned)w < 64u) {
                const unsigned short* src = acts + (size_t)(((b << 6) + hh) << 6 | w) * 256 + (cc << 6) + (c16 << 3);
                v = *reinterpret_cast<const uint4*>(src);
            }
            int dst = (dh * 66 + wp) * 128 + ((c16 << 4) ^ ((wp & 7) << 4));
            *reinterpret_cast<uint4*>(reinterpret_cast<char*>(sh.stage) + dst) = v;
        }
        __syncthreads();

        for (int off = 0; off < 9; ++off) {
            int kh = off / 3;            // LDS plane
            int kw = off - kh * 3 - 1;   // -1..1
            #pragma unroll
            for (int kk = 0; kk < 2; ++kk) {
                bf16x8 af[4], wf[4];
                #pragma unroll
                for (int t = 0; t < 4; ++t) {       // acts frag: w-tile t
                    int wp = (t << 4) + l15 + kw + 1;            // 0..65
                    int cb = (kk << 6) + (l4 << 4);              // byte in 128B row
                    int byte = (kh * 66 + wp) * 128 + (cb ^ ((wp & 7) << 4));
                    af[t] = *reinterpret_cast<const bf16x8*>(reinterpret_cast<const char*>(sh.stage) + byte);
                }
                const unsigned short* wbase = twT + (size_t)(off << 16)
                                            + (((wv << 6) + l15) << 8) + (cc << 6) + (kk << 5) + (l4 << 3);
                #pragma unroll
                for (int t = 0; t < 4; ++t)         // weight frag: co-tile t
                    wf[t] = *reinterpret_cast<const bf16x8*>(wbase + (t << 12));
                #pragma unroll
                for (int mt = 0; mt < 4; ++mt)
                    #pragma unroll
                    for (int nt = 0; nt < 4; ++nt) {
                        if (O == 0)
                            acc[mt][nt] = __builtin_amdgcn_mfma_f32_16x16x32_bf16(af[mt], wf[nt], acc[mt][nt], 0, 0, 0);
                        else
                            acc[mt][nt] = __builtin_amdgcn_mfma_f32_16x16x32_bf16(wf[mt], af[nt], acc[mt][nt], 0, 0, 0);
                    }
            }
        }
    }

    // ---- epilogue: LDS transpose to [co][w], coalesced NCHW store ----
    float qs = fabsf(*scale);
    for (int half = 0; half < 2; ++half) {
        __syncthreads();                      // staging LDS / previous half no longer needed
        if ((wv >> 1) == half) {
            if (O == 0) {
                #pragma unroll
                for (int nt = 0; nt < 4; ++nt) {
                    int co = (wv << 6) + (nt << 4) + l15;       // n-dim = co
                    float bb1 = bias[co];
                    float tbv = tb[(b << 8) + co];
                    int row = co & 127;
                    #pragma unroll
                    for (int mt = 0; mt < 4; ++mt)
                        #pragma unroll
                        for (int r = 0; r < 4; ++r) {
                            int wpos = (mt << 4) + (l4 << 2) + r;  // m-dim = w
                            float p = acc[mt][nt][r] * qs + bb1;   // fp32(I + b1)   (qs=1 exact)
                            sh.outbuf[row * 66 + wpos] = p + tbv;  // fp32(.. + tb)  np order
                        }
                }
            } else {
                #pragma unroll
                for (int mt = 0; mt < 4; ++mt)
                    #pragma unroll
                    for (int r = 0; r < 4; ++r) {
                        int co = (wv << 6) + (mt << 4) + (l4 << 2) + r;   // m-dim = co
                        float bb2 = bias[co];
                        int row = co & 127;
                        #pragma unroll
                        for (int nt = 0; nt < 4; ++nt) {
                            int wpos = (nt << 4) + l15;                   // n-dim = w
                            sh.outbuf[row * 66 + wpos] = acc[mt][nt][r] * qs + bb2;  // fp32(I + b2)
                        }
                    }
            }
        }
        __syncthreads();
        for (int idx = tid; idx < 4096; idx += 256) {
            int row = idx >> 5;               // 0..127
            int wq  = (idx & 31) << 1;        // 0,2,..,62
            int co  = (half << 7) + row;
            size_t gidx = ((size_t)((b << 8) + co) << 12) + (h << 6) + wq;
            float2 val;
            val.x = sh.outbuf[row * 66 + wq];
            val.y = sh.outbuf[row * 66 + wq + 1];
            if (O == 1) {                      // fp32(.. + x)  np order
                float2 rx = *reinterpret_cast<const float2*>(resid + gidx);
                val.x = val.x + rx.x;
                val.y = val.y + rx.y;
            }
            *reinterpret_cast<float2*>(out + gidx) = val;
        }
    }
}

extern "C" void kernel_launch(void* const* d_in, const int* in_sizes, int n_in,
                              void* d_out, int out_size, void* d_ws, size_t ws_size,
                              hipStream_t stream)
{
    const float* x      = (const float*)d_in[0];
    const float* te     = (const float*)d_in[1];
    const float* gn1_g  = (const float*)d_in[2];
    const float* gn1_b  = (const float*)d_in[3];
    const float* scale1 = (const float*)d_in[4];
    const float* W1     = (const float*)d_in[5];
    const float* b1     = (const float*)d_in[6];
    const float* Wt     = (const float*)d_in[7];
    const float* bt     = (const float*)d_in[8];
    const float* gn2_g  = (const float*)d_in[9];
    const float* gn2_b  = (const float*)d_in[10];
    const float* scale2 = (const float*)d_in[11];
    const float* W2     = (const float*)d_in[12];
    const float* b2     = (const float*)d_in[13];
    float* out = (float*)d_out;

    char* ws = (char*)d_ws;
    unsigned short* a1   = (unsigned short*)(ws + WS_A1);
    unsigned short* a2   = (unsigned short*)(ws + WS_A2);
    float*          out1 = (float*)(ws + WS_OUT1);
    unsigned short* tw1  = (unsigned short*)(ws + WS_TW1);
    unsigned short* tw2  = (unsigned short*)(ws + WS_TW2);
    float*          tbp  = (float*)(ws + WS_TB);
    float*          gn1m = (float*)(ws + WS_GN1);
    float*          gn1r = gn1m + 256;
    float*          gn2m = (float*)(ws + WS_GN2);
    float*          gn2r = gn2m + 256;

    k_gn_stats<<<256, 256, 0, stream>>>(x, gn1m, gn1r);
    k_tern<<<2304, 256, 0, stream>>>(W1, tw1);
    k_tern<<<2304, 256, 0, stream>>>(W2, tw2);
    k_tb<<<8, 256, 0, stream>>>(te, Wt, bt, tbp);
    k_norm_quant<<<512, 256, 0, stream>>>(x, gn1_g, gn1_b, gn1m, gn1r, scale1, a1);
    k_conv<0><<<512, 256, 0, stream>>>(a1, tw1, b1, tbp, scale1, nullptr, out1);
    k_gn_stats<<<256, 256, 0, stream>>>(out1, gn2m, gn2r);
    k_norm_quant<<<512, 256, 0, stream>>>(out1, gn2_g, gn2_b, gn2m, gn2r, scale2, a2);
    k_conv<1><<<512, 256, 0, stream>>>(a2, tw2, b2, nullptr, scale2, x, out);
}

// Round 6
// 322.683 us; speedup vs baseline: 1.2616x; 1.2616x over previous
//
#include <hip/hip_runtime.h>

typedef float f32x4 __attribute__((ext_vector_type(4)));
typedef __bf16 bf16x8 __attribute__((ext_vector_type(8)));
typedef unsigned int u32;

#define WTHR 0.001f

// ---------------- ws layout (bytes) ----------------
static constexpr size_t WS_A1   = 0;                       // ushort[8388608] bf16 bits, NHWC
static constexpr size_t WS_A2   = 16777216;                // ushort[8388608] NHWC
static constexpr size_t WS_OUT1 = 33554432;                // float[8388608], NCHW
static constexpr size_t WS_TW   = 67108864;                // ushort[2*9*256*256]  (tw1, then tw2 at +589824 elems)
static constexpr size_t WS_TB   = 69468160;                // float[8*256]
static constexpr size_t WS_GN1  = 69476352;                // float[512]: mean[256], rstd[256]
static constexpr size_t WS_GN2  = 69478400;                // float[512]

// ---------------- GN stats: EXACT numpy-fp32 pairwise, shuffle-tree ----------------
// One block per (b,g), slab = 32768 contiguous floats. Leaf t = thread t (128 floats,
// 8-acc stride-8 base case, combine ((r0+r1)+(r2+r3))+((r4+r5)+(r6+r7))); binary tree
// above via __shfl_down (st=1..32 within wave) + 4-way cross-wave combine — identical
// addition pairing to numpy pairwise_sum at every level.
__global__ __launch_bounds__(256)
void k_gn_stats(const float* __restrict__ x, float* __restrict__ mean, float* __restrict__ rstd)
{
    int bg = blockIdx.x;
    int t = threadIdx.x;
    int lane = t & 63, wv = t >> 6;
    const float4* A = reinterpret_cast<const float4*>(x + (size_t)bg * 32768 + (size_t)t * 128);
    __shared__ float red[4];
    __shared__ float Mv;

    float r0, r1, r2, r3, r4, r5, r6, r7;
    {
        float4 v0 = A[0], v1 = A[1];
        r0 = v0.x; r1 = v0.y; r2 = v0.z; r3 = v0.w;
        r4 = v1.x; r5 = v1.y; r6 = v1.z; r7 = v1.w;
        for (int i = 2; i < 32; i += 2) {
            float4 u0 = A[i], u1 = A[i + 1];
            r0 += u0.x; r1 += u0.y; r2 += u0.z; r3 += u0.w;
            r4 += u1.x; r5 += u1.y; r6 += u1.z; r7 += u1.w;
        }
    }
    float p = ((r0 + r1) + (r2 + r3)) + ((r4 + r5) + (r6 + r7));
    #pragma unroll
    for (int st = 1; st <= 32; st <<= 1) p = p + __shfl_down(p, st);
    if (lane == 0) red[wv] = p;
    __syncthreads();
    if (t == 0) Mv = ((red[0] + red[1]) + (red[2] + red[3])) / 32768.0f;
    __syncthreads();
    float mn = Mv;

    {
        float4 v0 = A[0], v1 = A[1];
        float d;
        d = v0.x - mn; r0 = __fmul_rn(d, d);
        d = v0.y - mn; r1 = __fmul_rn(d, d);
        d = v0.z - mn; r2 = __fmul_rn(d, d);
        d = v0.w - mn; r3 = __fmul_rn(d, d);
        d = v1.x - mn; r4 = __fmul_rn(d, d);
        d = v1.y - mn; r5 = __fmul_rn(d, d);
        d = v1.z - mn; r6 = __fmul_rn(d, d);
        d = v1.w - mn; r7 = __fmul_rn(d, d);
        for (int i = 2; i < 32; i += 2) {
            float4 u0 = A[i], u1 = A[i + 1];
            d = u0.x - mn; r0 = r0 + __fmul_rn(d, d);
            d = u0.y - mn; r1 = r1 + __fmul_rn(d, d);
            d = u0.z - mn; r2 = r2 + __fmul_rn(d, d);
            d = u0.w - mn; r3 = r3 + __fmul_rn(d, d);
            d = u1.x - mn; r4 = r4 + __fmul_rn(d, d);
            d = u1.y - mn; r5 = r5 + __fmul_rn(d, d);
            d = u1.z - mn; r6 = r6 + __fmul_rn(d, d);
            d = u1.w - mn; r7 = r7 + __fmul_rn(d, d);
        }
    }
    p = ((r0 + r1) + (r2 + r3)) + ((r4 + r5) + (r6 + r7));
    #pragma unroll
    for (int st = 1; st <= 32; st <<= 1) p = p + __shfl_down(p, st);
    if (lane == 0) red[wv] = p;
    __syncthreads();
    if (t == 0) {
        float var = ((red[0] + red[1]) + (red[2] + red[3])) / 32768.0f;
        mean[bg] = mn;
        rstd[bg] = __fdiv_rn(1.0f, __fsqrt_rn(var + 1e-5f));
    }
}

// ---------------- ternarize BOTH weight tensors: W[co][ci][kh][kw] -> twT[off][co][ci] ----------------
__global__ __launch_bounds__(256)
void k_tern(const float* __restrict__ W1, const float* __restrict__ W2, unsigned short* __restrict__ twT)
{
    int idx = blockIdx.x * 256 + threadIdx.x;        // 0..1179647 (block-uniform tensor select)
    int sel = idx >= 589824;
    const float* W = sel ? W2 : W1;
    int lid = idx - (sel ? 589824 : 0);
    int off = lid >> 16;
    int rem = lid & 65535;
    int co = rem >> 8, ci = rem & 255;
    float w = W[(size_t)((co << 8) | ci) * 9 + off];
    unsigned short tq = (w > WTHR) ? (unsigned short)0x3F80u
                      : ((w < -WTHR) ? (unsigned short)0xBF80u : (unsigned short)0u);
    twT[idx] = tq;
}

// ---------------- time bias: fp32 sequential FMA (BLAS order) ----------------
__global__ __launch_bounds__(256)
void k_tb(const float* __restrict__ te, const float* __restrict__ Wt, const float* __restrict__ bt,
          float* __restrict__ tb)
{
    int b = blockIdx.x, co = threadIdx.x;
    const float* wrow = Wt + (size_t)co * 512;
    const float* trow = te + (size_t)b * 512;
    float acc = 0.f;
    for (int t = 0; t < 512; ++t) {
        float w = wrow[t];
        float tw = (w > WTHR) ? 1.f : ((w < -WTHR) ? -1.f : 0.f);
        acc = __fmaf_rn(fmaxf(trow[t], 0.f), tw, acc);
    }
    tb[(b << 8) + co] = acc + bt[co];
}

// ---------------- norm + relu + quant: src NCHW f32 -> dst NHWC bf16 bits {0,1} ----------------
__global__ __launch_bounds__(256)
void k_norm_quant(const float* __restrict__ x, const float* __restrict__ gamma, const float* __restrict__ beta,
                  const float* __restrict__ mean, const float* __restrict__ rstd,
                  const float* __restrict__ scale, unsigned short* __restrict__ a)
{
    int blk = blockIdx.x;            // 512 = b*64+h
    int b = blk >> 6, h = blk & 63;
    int tid = threadIdx.x;
    __shared__ unsigned short T[64 * 264];     // [w][c], pitch 264 ushorts
    float s = fabsf(*scale);
    int w = tid & 63;
    int c0 = (tid >> 6) << 6;
    for (int o = 0; o < 8; ++o) {
        alignas(16) unsigned short r8[8];
        int bg = (b << 5) + ((c0 >> 3) + o);
        float mnv = mean[bg], rsv = rstd[bg];
        #pragma unroll
        for (int j = 0; j < 8; ++j) {
            int c = c0 + (o << 3) + j;
            float xv = x[((size_t)((b << 8) + c) << 12) + (h << 6) + w];
            float y = __fmul_rn(xv - mnv, rsv);
            y = y * gamma[c] + beta[c];
            y = fmaxf(y, 0.f);
            r8[j] = (rintf(__fdiv_rn(y, s)) >= 1.0f) ? (unsigned short)0x3F80u : (unsigned short)0u;
        }
        *reinterpret_cast<uint4*>(&T[w * 264 + c0 + (o << 3)]) = *reinterpret_cast<const uint4*>(r8);
    }
    __syncthreads();
    unsigned short* dst = a + ((size_t)blk << 14);
    #pragma unroll
    for (int j = 0; j < 8; ++j) {
        int e = (j << 11) + (tid << 3);          // element = w*256 + c
        int ww = e >> 8, c = e & 255;
        *reinterpret_cast<uint4*>(dst + e) = *reinterpret_cast<const uint4*>(&T[ww * 264 + c]);
    }
}

// ---------------- conv 3x3, implicit GEMM, bf16 MFMA ----------------
// Both: D[m=co][n=w] = W * acts. Grid 1024 = (b,h,co-half); XCD-chunked swizzle -> XCD k owns batch k.
// Staging: global_load_lds w16, pre-swizzled global source (LDS stays linear), no halo
// (w-edges handled by zero-masked fragments). O==0: out1 += b1 + tb; O==1: out += b2 + x.
template<int O>
__global__ __launch_bounds__(256, 4)
void k_conv(const unsigned short* __restrict__ acts,   // NHWC bf16 bits [8][64][64][256]
            const unsigned short* __restrict__ twT,    // [9][256][256] bf16 bits
            const float* __restrict__ bias,            // [256]
            const float* __restrict__ tb,              // [8][256] (O==0)
            const float* __restrict__ scale,
            const float* __restrict__ resid,           // x NCHW (O==1)
            float* __restrict__ out)                   // NCHW f32
{
    int blk0 = blockIdx.x;
    int logical = ((blk0 & 7) << 7) + (blk0 >> 3);   // XCD k -> logical [k*128,(k+1)*128) = batch k
    int half = logical & 1;
    int bh = logical >> 1;
    int b = bh >> 6, h = bh & 63;
    int tid = threadIdx.x;
    int lane = tid & 63, wv = tid >> 6;
    int l15 = lane & 15, l4 = lane >> 4;

    __shared__ unsigned short Ls[3 * 64 * 64];   // 24576 B; row (dh*64+w)*128B, 16B slots XOR-swizzled by w&7

    f32x4 acc[2][4];
    #pragma unroll
    for (int i = 0; i < 2; ++i)
        #pragma unroll
        for (int j = 0; j < 4; ++j) acc[i][j] = (f32x4){0.f, 0.f, 0.f, 0.f};

    int lw = lane >> 3;                 // 0..7: row within 1KB chunk = w sub-offset
    int lc = (lane & 7) ^ lw;           // pre-swizzled source granule (slot s holds granule s^(w&7))
    int cobase = (half << 7) + (wv << 5);

    for (int cc = 0; cc < 4; ++cc) {
        __syncthreads();                             // previous tile fully consumed
        #pragma unroll
        for (int i = 0; i < 6; ++i) {
            int chunk = wv * 6 + i;                  // 0..23, 1KB each (8 w-rows)
            int dh = chunk >> 3;
            int w0 = (chunk & 7) << 3;
            int hh = h + dh - 1;
            char* ldst = (char*)Ls + chunk * 1024;
            if ((unsigned)hh < 64u) {
                const unsigned short* g = acts
                    + ((size_t)(((b << 6) + hh) << 6) + (w0 + lw)) * 256 + (cc << 6) + (lc << 3);
                __builtin_amdgcn_global_load_lds(
                    (const __attribute__((address_space(1))) u32*)g,
                    (__attribute__((address_space(3))) u32*)ldst, 16, 0, 0);
            } else {
                *reinterpret_cast<uint4*>(ldst + lane * 16) = (uint4){0u, 0u, 0u, 0u};
            }
        }
        __syncthreads();                             // drains vmcnt+lgkm (compiler)

        #pragma unroll
        for (int off = 0; off < 9; ++off) {
            const int kh = off / 3;
            const int kw = off % 3 - 1;
            #pragma unroll
            for (int kk = 0; kk < 2; ++kk) {
                bf16x8 af[4], wf[2];
                #pragma unroll
                for (int nt = 0; nt < 4; ++nt) {
                    int wi = (nt << 4) + l15 + kw;             // input w for output col
                    bool ok = (unsigned)wi < 64u;
                    int wc = ok ? wi : 0;
                    int byte = ((kh << 6) + wc) * 128 + (((kk << 6) + (l4 << 4)) ^ ((wc & 7) << 4));
                    uint4 uv = *reinterpret_cast<const uint4*>((const char*)Ls + byte);
                    u32 m = ok ? 0xFFFFFFFFu : 0u;
                    uv.x &= m; uv.y &= m; uv.z &= m; uv.w &= m;
                    af[nt] = *reinterpret_cast<const bf16x8*>(&uv);
                }
                const unsigned short* wb = twT + ((size_t)off << 16)
                    + ((size_t)(cobase + l15) << 8) + (cc << 6) + (kk << 5) + (l4 << 3);
                wf[0] = *reinterpret_cast<const bf16x8*>(wb);
                wf[1] = *reinterpret_cast<const bf16x8*>(wb + 4096);   // +16 co rows
                #pragma unroll
                for (int mt = 0; mt < 2; ++mt)
                    #pragma unroll
                    for (int nt = 0; nt < 4; ++nt)
                        acc[mt][nt] = __builtin_amdgcn_mfma_f32_16x16x32_bf16(wf[mt], af[nt], acc[mt][nt], 0, 0, 0);
            }
        }
    }

    // ---- epilogue: direct NCHW stores, 64B quarter-wave segments ----
    float qs = fabsf(*scale);
    #pragma unroll
    for (int mt = 0; mt < 2; ++mt)
        #pragma unroll
        for (int r = 0; r < 4; ++r) {
            int co = cobase + (mt << 4) + (l4 << 2) + r;
            float bb = bias[co];
            float tv = (O == 0) ? tb[(b << 8) + co] : 0.f;
            size_t rowb = ((size_t)((b << 8) + co) << 12) + (h << 6);
            #pragma unroll
            for (int nt = 0; nt < 4; ++nt) {
                int w = (nt << 4) + l15;
                float v = __fmul_rn(acc[mt][nt][r], qs) + bb;   // fp32(I + b)
                if (O == 0) v = v + tv;                          // fp32(.. + tb)
                else        v = v + resid[rowb + w];             // fp32(.. + x)
                out[rowb + w] = v;
            }
        }
}

extern "C" void kernel_launch(void* const* d_in, const int* in_sizes, int n_in,
                              void* d_out, int out_size, void* d_ws, size_t ws_size,
                              hipStream_t stream)
{
    const float* x      = (const float*)d_in[0];
    const float* te     = (const float*)d_in[1];
    const float* gn1_g  = (const float*)d_in[2];
    const float* gn1_b  = (const float*)d_in[3];
    const float* scale1 = (const float*)d_in[4];
    const float* W1     = (const float*)d_in[5];
    const float* b1     = (const float*)d_in[6];
    const float* Wt     = (const float*)d_in[7];
    const float* bt     = (const float*)d_in[8];
    const float* gn2_g  = (const float*)d_in[9];
    const float* gn2_b  = (const float*)d_in[10];
    const float* scale2 = (const float*)d_in[11];
    const float* W2     = (const float*)d_in[12];
    const float* b2     = (const float*)d_in[13];
    float* out = (float*)d_out;

    char* ws = (char*)d_ws;
    unsigned short* a1   = (unsigned short*)(ws + WS_A1);
    unsigned short* a2   = (unsigned short*)(ws + WS_A2);
    float*          out1 = (float*)(ws + WS_OUT1);
    unsigned short* tw   = (unsigned short*)(ws + WS_TW);
    unsigned short* tw1  = tw;
    unsigned short* tw2  = tw + 589824;
    float*          tbp  = (float*)(ws + WS_TB);
    float*          gn1m = (float*)(ws + WS_GN1);
    float*          gn1r = gn1m + 256;
    float*          gn2m = (float*)(ws + WS_GN2);
    float*          gn2r = gn2m + 256;

    k_gn_stats<<<256, 256, 0, stream>>>(x, gn1m, gn1r);
    k_tern<<<4608, 256, 0, stream>>>(W1, W2, tw);
    k_tb<<<8, 256, 0, stream>>>(te, Wt, bt, tbp);
    k_norm_quant<<<512, 256, 0, stream>>>(x, gn1_g, gn1_b, gn1m, gn1r, scale1, a1);
    k_conv<0><<<1024, 256, 0, stream>>>(a1, tw1, b1, tbp, scale1, nullptr, out1);
    k_gn_stats<<<256, 256, 0, stream>>>(out1, gn2m, gn2r);
    k_norm_quant<<<512, 256, 0, stream>>>(out1, gn2_g, gn2_b, gn2m, gn2r, scale2, a2);
    k_conv<1><<<1024, 256, 0, stream>>>(a2, tw2, b2, nullptr, scale2, x, out);
}

// Round 7
// 318.660 us; speedup vs baseline: 1.2775x; 1.0126x over previous
//
#include <hip/hip_runtime.h>

typedef float f32x4 __attribute__((ext_vector_type(4)));
typedef __bf16 bf16x8 __attribute__((ext_vector_type(8)));
typedef unsigned int u32;

#define WTHR 0.001f

// ---------------- ws layout (bytes) ----------------
static constexpr size_t WS_A1   = 0;                       // ushort[8388608] bf16 bits, NHWC
static constexpr size_t WS_A2   = 16777216;                // ushort[8388608] NHWC
static constexpr size_t WS_OUT1 = 33554432;                // float[8388608], NCHW
static constexpr size_t WS_TW   = 67108864;                // ushort[2*589824]
static constexpr size_t WS_TB   = 69468160;                // float[8*256]
static constexpr size_t WS_GN1  = 69476352;                // float[512]
static constexpr size_t WS_GN2  = 69478400;                // float[512]

// ---------------- GN stats: EXACT numpy-fp32 pairwise, shuffle-tree (unchanged, bit-exact) ----------------
__global__ __launch_bounds__(256)
void k_gn_stats(const float* __restrict__ x, float* __restrict__ mean, float* __restrict__ rstd)
{
    int bg = blockIdx.x;
    int t = threadIdx.x;
    int lane = t & 63, wv = t >> 6;
    const float4* A = reinterpret_cast<const float4*>(x + (size_t)bg * 32768 + (size_t)t * 128);
    __shared__ float red[4];
    __shared__ float Mv;

    float r0, r1, r2, r3, r4, r5, r6, r7;
    {
        float4 v0 = A[0], v1 = A[1];
        r0 = v0.x; r1 = v0.y; r2 = v0.z; r3 = v0.w;
        r4 = v1.x; r5 = v1.y; r6 = v1.z; r7 = v1.w;
        for (int i = 2; i < 32; i += 2) {
            float4 u0 = A[i], u1 = A[i + 1];
            r0 += u0.x; r1 += u0.y; r2 += u0.z; r3 += u0.w;
            r4 += u1.x; r5 += u1.y; r6 += u1.z; r7 += u1.w;
        }
    }
    float p = ((r0 + r1) + (r2 + r3)) + ((r4 + r5) + (r6 + r7));
    #pragma unroll
    for (int st = 1; st <= 32; st <<= 1) p = p + __shfl_down(p, st);
    if (lane == 0) red[wv] = p;
    __syncthreads();
    if (t == 0) Mv = ((red[0] + red[1]) + (red[2] + red[3])) / 32768.0f;
    __syncthreads();
    float mn = Mv;

    {
        float4 v0 = A[0], v1 = A[1];
        float d;
        d = v0.x - mn; r0 = __fmul_rn(d, d);
        d = v0.y - mn; r1 = __fmul_rn(d, d);
        d = v0.z - mn; r2 = __fmul_rn(d, d);
        d = v0.w - mn; r3 = __fmul_rn(d, d);
        d = v1.x - mn; r4 = __fmul_rn(d, d);
        d = v1.y - mn; r5 = __fmul_rn(d, d);
        d = v1.z - mn; r6 = __fmul_rn(d, d);
        d = v1.w - mn; r7 = __fmul_rn(d, d);
        for (int i = 2; i < 32; i += 2) {
            float4 u0 = A[i], u1 = A[i + 1];
            d = u0.x - mn; r0 = r0 + __fmul_rn(d, d);
            d = u0.y - mn; r1 = r1 + __fmul_rn(d, d);
            d = u0.z - mn; r2 = r2 + __fmul_rn(d, d);
            d = u0.w - mn; r3 = r3 + __fmul_rn(d, d);
            d = u1.x - mn; r4 = r4 + __fmul_rn(d, d);
            d = u1.y - mn; r5 = r5 + __fmul_rn(d, d);
            d = u1.z - mn; r6 = r6 + __fmul_rn(d, d);
            d = u1.w - mn; r7 = r7 + __fmul_rn(d, d);
        }
    }
    p = ((r0 + r1) + (r2 + r3)) + ((r4 + r5) + (r6 + r7));
    #pragma unroll
    for (int st = 1; st <= 32; st <<= 1) p = p + __shfl_down(p, st);
    if (lane == 0) red[wv] = p;
    __syncthreads();
    if (t == 0) {
        float var = ((red[0] + red[1]) + (red[2] + red[3])) / 32768.0f;
        mean[bg] = mn;
        rstd[bg] = __fdiv_rn(1.0f, __fsqrt_rn(var + 1e-5f));
    }
}

// ---------------- ternarize: one block per (tensor,co); coalesced read, LDS reorder ----------------
__global__ __launch_bounds__(256)
void k_tern(const float* __restrict__ W1, const float* __restrict__ W2, unsigned short* __restrict__ twT)
{
    int blk = blockIdx.x;                 // 0..511
    int co = blk & 255;
    const float* src = ((blk & 256) ? W2 : W1) + (size_t)co * 2304;
    unsigned short* base = twT + (size_t)(blk >> 8) * 589824 + (co << 8);
    int t = threadIdx.x;
    __shared__ unsigned short Q[2304];    // [ci*9+off]
    #pragma unroll
    for (int i = 0; i < 9; ++i) {
        float w = src[t + (i << 8)];
        Q[t + (i << 8)] = (w > WTHR) ? (unsigned short)0x3F80u
                        : ((w < -WTHR) ? (unsigned short)0xBF80u : (unsigned short)0u);
    }
    __syncthreads();
    #pragma unroll
    for (int i = 0; i < 9; ++i) {
        int idx = t + (i << 8);           // 2304 = 9*256
        int off = idx >> 8, ci = idx & 255;
        base[off * 65536 + ci] = Q[ci * 9 + off];
    }
}

// ---------------- time bias: fp32 sequential FMA (bit-exact vs np; DO NOT TOUCH) ----------------
__global__ __launch_bounds__(256)
void k_tb(const float* __restrict__ te, const float* __restrict__ Wt, const float* __restrict__ bt,
          float* __restrict__ tb)
{
    int b = blockIdx.x, co = threadIdx.x;
    const float* wrow = Wt + (size_t)co * 512;
    const float* trow = te + (size_t)b * 512;
    float acc = 0.f;
    for (int t = 0; t < 512; ++t) {
        float w = wrow[t];
        float tw = (w > WTHR) ? 1.f : ((w < -WTHR) ? -1.f : 0.f);
        acc = __fmaf_rn(fmaxf(trow[t], 0.f), tw, acc);
    }
    tb[(b << 8) + co] = acc + bt[co];
}

// ---------------- norm + relu + quant: NCHW f32 -> NHWC bf16 bits; XOR-swizzled LDS, conflict-free ----------------
__global__ __launch_bounds__(256)
void k_norm_quant(const float* __restrict__ x, const float* __restrict__ gamma, const float* __restrict__ beta,
                  const float* __restrict__ mean, const float* __restrict__ rstd,
                  const float* __restrict__ scale, unsigned short* __restrict__ a)
{
    int blk = blockIdx.x;            // 512 = b*64+h
    int b = blk >> 6, h = blk & 63;
    int tid = threadIdx.x;
    __shared__ unsigned short T[64 * 256];     // 32KB: [w][granule], granule swizzled by ^ (w&31)
    float s = fabsf(*scale);
    int w = tid & 63;
    int g0 = (tid >> 6) << 3;                  // first granule of this thread's 64-c slab
    #pragma unroll
    for (int o = 0; o < 8; ++o) {
        int gc = g0 + o;                       // granule = c>>3, 0..31
        alignas(16) unsigned short r8[8];
        float mnv = mean[(b << 5) + gc], rsv = rstd[(b << 5) + gc];
        #pragma unroll
        for (int j = 0; j < 8; ++j) {
            int c = (gc << 3) + j;
            float xv = x[((size_t)((b << 8) + c) << 12) + (h << 6) + w];
            float y = __fmul_rn(xv - mnv, rsv);
            y = y * gamma[c] + beta[c];
            y = fmaxf(y, 0.f);
            r8[j] = (rintf(__fdiv_rn(y, s)) >= 1.0f) ? (unsigned short)0x3F80u : (unsigned short)0u;
        }
        int gs = gc ^ (w & 31);
        *reinterpret_cast<uint4*>(&T[(w << 8) + (gs << 3)]) = *reinterpret_cast<const uint4*>(r8);
    }
    __syncthreads();
    unsigned short* dst = a + ((size_t)blk << 14);
    #pragma unroll
    for (int j = 0; j < 8; ++j) {
        int e = (j << 11) + (tid << 3);        // element = w*256 + c
        int ww = e >> 8;
        int gs = (tid & 31) ^ (ww & 31);
        *reinterpret_cast<uint4*>(dst + e) = *reinterpret_cast<const uint4*>(&T[(ww << 8) + (gs << 3)]);
    }
}

// ---------------- conv 3x3, implicit GEMM, bf16 MFMA, 2-deep software pipeline ----------------
// D[m=co][n=w] = W * acts. Grid 1024 = (b,h,co-half); XCD-chunked swizzle (XCD k owns batch k).
// Pipeline: step s=(off*2+kk) in 0..17; issue s+1's 4 ds_read + 2 wf loads, then MFMA step s.
template<int O>
__global__ __launch_bounds__(256, 4)
void k_conv(const unsigned short* __restrict__ acts,   // NHWC bf16 bits [8][64][64][256]
            const unsigned short* __restrict__ twT,    // [9][256][256] bf16 bits
            const float* __restrict__ bias,            // [256]
            const float* __restrict__ tb,              // [8][256] (O==0)
            const float* __restrict__ scale,
            const float* __restrict__ resid,           // x NCHW (O==1)
            float* __restrict__ out)                   // NCHW f32
{
    int blk0 = blockIdx.x;
    int logical = ((blk0 & 7) << 7) + (blk0 >> 3);
    int half = logical & 1;
    int bh = logical >> 1;
    int b = bh >> 6, h = bh & 63;
    int tid = threadIdx.x;
    int lane = tid & 63, wv = tid >> 6;
    int l15 = lane & 15, l4 = lane >> 4;

    __shared__ unsigned short Ls[3 * 64 * 64];   // 24576 B

    f32x4 acc[2][4];
    #pragma unroll
    for (int i = 0; i < 2; ++i)
        #pragma unroll
        for (int j = 0; j < 4; ++j) acc[i][j] = (f32x4){0.f, 0.f, 0.f, 0.f};

    int lw = lane >> 3;
    int lc = (lane & 7) ^ lw;
    int cobase = (half << 7) + (wv << 5);

    for (int cc = 0; cc < 4; ++cc) {
        __syncthreads();
        #pragma unroll
        for (int i = 0; i < 6; ++i) {
            int chunk = wv * 6 + i;
            int dh = chunk >> 3;
            int w0 = (chunk & 7) << 3;
            int hh = h + dh - 1;
            char* ldst = (char*)Ls + chunk * 1024;
            if ((unsigned)hh < 64u) {
                const unsigned short* g = acts
                    + ((size_t)(((b << 6) + hh) << 6) + (w0 + lw)) * 256 + (cc << 6) + (lc << 3);
                __builtin_amdgcn_global_load_lds(
                    (const __attribute__((address_space(1))) u32*)g,
                    (__attribute__((address_space(3))) u32*)ldst, 16, 0, 0);
            } else {
                *reinterpret_cast<uint4*>(ldst + lane * 16) = (uint4){0u, 0u, 0u, 0u};
            }
        }
        __syncthreads();

        // ---- load helper: step s = off*2+kk ----
        auto loadStep = [&](int s, bf16x8* af, bf16x8* wf) {
            int off = s >> 1;
            int kh = off / 3;
            int kwv = off % 3 - 1;
            int kk = s & 1;
            #pragma unroll
            for (int nt = 0; nt < 4; ++nt) {
                int wi = (nt << 4) + l15 + kwv;
                bool ok = (unsigned)wi < 64u;
                int wc = ok ? wi : 0;
                int byte = ((kh << 6) + wc) * 128 + (((kk << 6) + (l4 << 4)) ^ ((wc & 7) << 4));
                uint4 uv = *reinterpret_cast<const uint4*>((const char*)Ls + byte);
                u32 m = ok ? 0xFFFFFFFFu : 0u;
                uv.x &= m; uv.y &= m; uv.z &= m; uv.w &= m;
                af[nt] = *reinterpret_cast<const bf16x8*>(&uv);
            }
            const unsigned short* wb = twT + ((size_t)off << 16)
                + ((size_t)(cobase + l15) << 8) + (cc << 6) + (kk << 5) + (l4 << 3);
            wf[0] = *reinterpret_cast<const bf16x8*>(wb);
            wf[1] = *reinterpret_cast<const bf16x8*>(wb + 4096);
        };

        bf16x8 afA[4], afB[4], wfA[2], wfB[2];
        loadStep(0, afA, wfA);
        #pragma unroll
        for (int s = 0; s < 18; ++s) {
            if (s < 17) {
                if (s & 1) loadStep(s + 1, afA, wfA);
                else       loadStep(s + 1, afB, wfB);
            }
            const bf16x8* af = (s & 1) ? afB : afA;
            const bf16x8* wf = (s & 1) ? wfB : wfA;
            #pragma unroll
            for (int mt = 0; mt < 2; ++mt)
                #pragma unroll
                for (int nt = 0; nt < 4; ++nt)
                    acc[mt][nt] = __builtin_amdgcn_mfma_f32_16x16x32_bf16(wf[mt], af[nt], acc[mt][nt], 0, 0, 0);
        }
    }

    // ---- epilogue: direct NCHW stores ----
    float qs = fabsf(*scale);
    #pragma unroll
    for (int mt = 0; mt < 2; ++mt)
        #pragma unroll
        for (int r = 0; r < 4; ++r) {
            int co = cobase + (mt << 4) + (l4 << 2) + r;
            float bb = bias[co];
            float tv = (O == 0) ? tb[(b << 8) + co] : 0.f;
            size_t rowb = ((size_t)((b << 8) + co) << 12) + (h << 6);
            #pragma unroll
            for (int nt = 0; nt < 4; ++nt) {
                int w = (nt << 4) + l15;
                float v = __fmul_rn(acc[mt][nt][r], qs) + bb;
                if (O == 0) v = v + tv;
                else        v = v + resid[rowb + w];
                out[rowb + w] = v;
            }
        }
}

extern "C" void kernel_launch(void* const* d_in, const int* in_sizes, int n_in,
                              void* d_out, int out_size, void* d_ws, size_t ws_size,
                              hipStream_t stream)
{
    const float* x      = (const float*)d_in[0];
    const float* te     = (const float*)d_in[1];
    const float* gn1_g  = (const float*)d_in[2];
    const float* gn1_b  = (const float*)d_in[3];
    const float* scale1 = (const float*)d_in[4];
    const float* W1     = (const float*)d_in[5];
    const float* b1     = (const float*)d_in[6];
    const float* Wt     = (const float*)d_in[7];
    const float* bt     = (const float*)d_in[8];
    const float* gn2_g  = (const float*)d_in[9];
    const float* gn2_b  = (const float*)d_in[10];
    const float* scale2 = (const float*)d_in[11];
    const float* W2     = (const float*)d_in[12];
    const float* b2     = (const float*)d_in[13];
    float* out = (float*)d_out;

    char* ws = (char*)d_ws;
    unsigned short* a1   = (unsigned short*)(ws + WS_A1);
    unsigned short* a2   = (unsigned short*)(ws + WS_A2);
    float*          out1 = (float*)(ws + WS_OUT1);
    unsigned short* tw   = (unsigned short*)(ws + WS_TW);
    unsigned short* tw1  = tw;
    unsigned short* tw2  = tw + 589824;
    float*          tbp  = (float*)(ws + WS_TB);
    float*          gn1m = (float*)(ws + WS_GN1);
    float*          gn1r = gn1m + 256;
    float*          gn2m = (float*)(ws + WS_GN2);
    float*          gn2r = gn2m + 256;

    k_gn_stats<<<256, 256, 0, stream>>>(x, gn1m, gn1r);
    k_tern<<<512, 256, 0, stream>>>(W1, W2, tw);
    k_tb<<<8, 256, 0, stream>>>(te, Wt, bt, tbp);
    k_norm_quant<<<512, 256, 0, stream>>>(x, gn1_g, gn1_b, gn1m, gn1r, scale1, a1);
    k_conv<0><<<1024, 256, 0, stream>>>(a1, tw1, b1, tbp, scale1, nullptr, out1);
    k_gn_stats<<<256, 256, 0, stream>>>(out1, gn2m, gn2r);
    k_norm_quant<<<512, 256, 0, stream>>>(out1, gn2_g, gn2_b, gn2m, gn2r, scale2, a2);
    k_conv<1><<<1024, 256, 0, stream>>>(a2, tw2, b2, nullptr, scale2, x, out);
}